// Round 10
// baseline (392.162 us; speedup 1.0000x reference)
//
#include <hip/hip_runtime.h>
#include <math.h>

// ReDrafterHead: B=64, H=4096, D=512, G3=1536, V=32000, STEPS=4
// Round 14 = exact R13 (354.3us, best) + ONE isolated change:
// k_reduce_embed ELIMINATED (4 dispatches; measured dispatch overhead ~6us).
// k_logits writes argmax partials TRANSPOSED (pvT[row*512+blk]) so the fused
// scan in gates-l0 mat0 blocks is coalesced (R12's regression mechanism was
// the strided scan). Token selection = total-order max (order-independent,
// same token); x path = identical embed gather + split2 + identical MFMA
// order -> gi0 bitwise identical. Step 0 writes exact zeros. 25 dispatches.

typedef __attribute__((ext_vector_type(8))) short short8;   // 8 bf16
typedef __attribute__((ext_vector_type(4))) float f32x4;

__device__ __forceinline__ unsigned short f2bf_rne(float x) {
    unsigned u = __float_as_uint(x);
    unsigned r = (u + 0x7fffu + ((u >> 16) & 1u)) >> 16;
    return (unsigned short)r;
}
// hi = truncate; lo = RNE of residual. 3-pass MFMA error ~2^-16 rel.
__device__ __forceinline__ void split2(float x, unsigned short& hi, unsigned short& lo) {
    unsigned u = __float_as_uint(x);
    hi = (unsigned short)(u >> 16);
    float r = x - __uint_as_float(u & 0xffff0000u);
    lo = f2bf_rne(r);
}

// store one element into swizzled bf16 hi/lo planes, row stride 512 elems.
__device__ __forceinline__ void store_plane(unsigned short* hiP, unsigned short* loP,
                                            int m, int d, float v) {
    int s = d >> 6, cl = (d >> 3) & 7, e = d & 7;
    int off = m * 512 + s * 64 + ((cl ^ (m & 7)) * 8) + e;
    unsigned short hi, lo; split2(v, hi, lo);
    hiP[off] = hi; loP[off] = lo;
}

__device__ __forceinline__ void gload16(const void* g, void* lds) {
    __builtin_amdgcn_global_load_lds(
        (const __attribute__((address_space(1))) unsigned int*)g,
        (__attribute__((address_space(3))) unsigned int*)lds, 16, 0, 0);
}

// ---------------------------------------------------------------------------
// Weight pre-split: W[N][K] fp32 -> swizzled bf16 planes, tile-major:
// ushort off = ((nt*(K/64) + ks)*128 + row)*64 + ((c8&7)^(row&7))*8
// ---------------------------------------------------------------------------
__device__ __forceinline__ void split_w_body(
    const float* __restrict__ W, unsigned short* __restrict__ H,
    unsigned short* __restrict__ L, size_t g, int kclog)
{
    int n  = (int)(g >> kclog);
    int c8 = (int)g & ((1 << kclog) - 1);
    const float* src = W + g * 8;
    float4 v0 = *(const float4*)src;
    float4 v1 = *(const float4*)(src + 4);
    unsigned short h[8], l[8];
    split2(v0.x,h[0],l[0]); split2(v0.y,h[1],l[1]); split2(v0.z,h[2],l[2]); split2(v0.w,h[3],l[3]);
    split2(v1.x,h[4],l[4]); split2(v1.y,h[5],l[5]); split2(v1.z,h[6],l[6]); split2(v1.w,h[7],l[7]);
    uint4 ph = make_uint4((unsigned)h[0]|((unsigned)h[1]<<16), (unsigned)h[2]|((unsigned)h[3]<<16),
                          (unsigned)h[4]|((unsigned)h[5]<<16), (unsigned)h[6]|((unsigned)h[7]<<16));
    uint4 pl = make_uint4((unsigned)l[0]|((unsigned)l[1]<<16), (unsigned)l[2]|((unsigned)l[3]<<16),
                          (unsigned)l[4]|((unsigned)l[5]<<16), (unsigned)l[6]|((unsigned)l[7]<<16));
    int nt = n >> 7, row = n & 127;
    int ksi = c8 >> 3;
    int slot = (c8 & 7) ^ (row & 7);
    int tpr = 1 << (kclog - 3);                 // tiles per row-tile = K/64
    size_t off = ((size_t)(nt * tpr + ksi) * 128 + row) * 64 + slot * 8;
    *(uint4*)(H + off) = ph;
    *(uint4*)(L + off) = pl;
}

__global__ __launch_bounds__(256) void k_split_W(
    const float* __restrict__ W, unsigned short* __restrict__ H,
    unsigned short* __restrict__ L, int kclog)
{
    size_t g = (size_t)blockIdx.x * 256 + threadIdx.x;
    split_w_body(W, H, L, g, kclog);
}

// 4 GRU weight matrices in one launch: grid (384, 4), blockIdx.y picks mat.
__global__ __launch_bounds__(256) void k_split_gw(
    const float* __restrict__ w0, const float* __restrict__ w1,
    const float* __restrict__ w2, const float* __restrict__ w3,
    unsigned short* __restrict__ H, unsigned short* __restrict__ L)
{
    int mat = blockIdx.y;
    const float* W = mat == 0 ? w0 : mat == 1 ? w1 : mat == 2 ? w2 : w3;
    size_t g = (size_t)blockIdx.x * 256 + threadIdx.x;     // < 98304
    split_w_body(W, H + (size_t)mat * 786432, L + (size_t)mat * 786432, g, 6);
}

// ---------------------------------------------------------------------------
// split hidden[64,4096] fp32 -> swizzled bf16 planes (row stride 8192 B)
// ---------------------------------------------------------------------------
__global__ __launch_bounds__(256) void k_split_A(
    const float* __restrict__ hidden, char* __restrict__ hidH, char* __restrict__ hidL)
{
    int g = blockIdx.x * 256 + threadIdx.x;   // 32768 chunks
    int m = g >> 9;
    int cc = g & 511;
    int s = cc >> 3, cl = cc & 7;
    const float* src = hidden + m * 4096 + cc * 8;
    float4 v0 = *(const float4*)src;
    float4 v1 = *(const float4*)(src + 4);
    unsigned short h[8], l[8];
    split2(v0.x,h[0],l[0]); split2(v0.y,h[1],l[1]); split2(v0.z,h[2],l[2]); split2(v0.w,h[3],l[3]);
    split2(v1.x,h[4],l[4]); split2(v1.y,h[5],l[5]); split2(v1.z,h[6],l[6]); split2(v1.w,h[7],l[7]);
    uint4 ph = make_uint4((unsigned)h[0]|((unsigned)h[1]<<16), (unsigned)h[2]|((unsigned)h[3]<<16),
                          (unsigned)h[4]|((unsigned)h[5]<<16), (unsigned)h[6]|((unsigned)h[7]<<16));
    uint4 pl = make_uint4((unsigned)l[0]|((unsigned)l[1]<<16), (unsigned)l[2]|((unsigned)l[3]<<16),
                          (unsigned)l[4]|((unsigned)l[5]<<16), (unsigned)l[6]|((unsigned)l[7]<<16));
    int off = m * 8192 + s * 128 + ((cl ^ (m & 7)) * 16);
    *(uint4*)(hidH + off) = ph;
    *(uint4*)(hidL + off) = pl;
}

// ---------------------------------------------------------------------------
// Shared MFMA inner core: one 64-k tile from LDS buffers into acc[4].
// ---------------------------------------------------------------------------
__device__ __forceinline__ void mfma_core(
    const unsigned short* __restrict__ AsH0, const unsigned short* __restrict__ AsL0,
    const unsigned short* __restrict__ BsH0, const unsigned short* __restrict__ BsL0,
    int wv, int lr, int lh, f32x4* acc)
{
#pragma unroll
    for (int kk2 = 0; kk2 < 2; ++kk2) {
        int aoff = lr * 64 + (((kk2 * 4 + lh) ^ (lr & 7)) * 8);
        short8 ah[4], al[4];
#pragma unroll
        for (int mt = 0; mt < 4; ++mt) {
            ah[mt] = *(const short8*)(AsH0 + mt * 1024 + aoff);
            al[mt] = *(const short8*)(AsL0 + mt * 1024 + aoff);
        }
        int brow = wv * 16 + lr;
        int boff = brow * 64 + (((kk2 * 4 + lh) ^ (brow & 7)) * 8);
        short8 bh = *(const short8*)(BsH0 + boff);
        short8 bl = *(const short8*)(BsL0 + boff);
#pragma unroll
        for (int mt = 0; mt < 4; ++mt) {
            acc[mt] = __builtin_amdgcn_mfma_f32_16x16x32_bf16(ah[mt], bh, acc[mt], 0, 0, 0);
            acc[mt] = __builtin_amdgcn_mfma_f32_16x16x32_bf16(ah[mt], bl, acc[mt], 0, 0, 0);
            acc[mt] = __builtin_amdgcn_mfma_f32_16x16x32_bf16(al[mt], bh, acc[mt], 0, 0, 0);
        }
    }
}

__device__ __forceinline__ void epilogue_write(
    float* __restrict__ C, int ldc, int n0, int wv, int lr, int lh, const f32x4* acc)
{
#pragma unroll
    for (int mt = 0; mt < 4; ++mt)
#pragma unroll
        for (int i = 0; i < 4; ++i) {
            int mm = mt * 16 + lh * 4 + i;
            C[mm * ldc + n0 + wv * 16 + lr] = acc[mt][i];
        }
}

// ---------------------------------------------------------------------------
// 4-wave plane GEMM (256 threads), NT=64, 64 KiB LDS -> 2 blocks/CU.
// ---------------------------------------------------------------------------
__device__ __forceinline__ void mfma_gemm4(
    const char* __restrict__ AH, const char* __restrict__ AL, int AstrideB, int akk0,
    const unsigned short* __restrict__ BH, const unsigned short* __restrict__ BL,
    size_t btileU, int nk,
    float* __restrict__ C, int ldc, int n0,
    unsigned short (*AsH)[4096], unsigned short (*AsL)[4096],
    unsigned short (*BsH)[4096], unsigned short (*BsL)[4096])
{
    const int tid  = threadIdx.x;
    const int wv   = tid >> 6;
    const int lane = tid & 63;
    const int lr   = lane & 15;
    const int lh   = lane >> 4;
    const int ar1  = wv * 16 + (lane >> 3);   // A staging row (call 1)
    const int acp  = lane & 7;                // A staging chunk

    f32x4 acc[4];
#pragma unroll
    for (int i = 0; i < 4; ++i) acc[i] = (f32x4){0.f, 0.f, 0.f, 0.f};

    auto stage = [&](int t, int p) {
        const int kaB = (akk0 + t * 64) * 2;
        gload16(AH + ar1 * AstrideB + kaB + acp * 16,       (char*)AsH[p] + wv * 2048);
        gload16(AH + (ar1 + 8) * AstrideB + kaB + acp * 16, (char*)AsH[p] + wv * 2048 + 1024);
        gload16(AL + ar1 * AstrideB + kaB + acp * 16,       (char*)AsL[p] + wv * 2048);
        gload16(AL + (ar1 + 8) * AstrideB + kaB + acp * 16, (char*)AsL[p] + wv * 2048 + 1024);
        const char* bH = (const char*)BH + (btileU + (size_t)t * 8192) * 2;
        const char* bL = (const char*)BL + (btileU + (size_t)t * 8192) * 2;
        gload16(bH + wv * 2048 +        lane * 16, (char*)BsH[p] + wv * 2048);
        gload16(bH + wv * 2048 + 1024 + lane * 16, (char*)BsH[p] + wv * 2048 + 1024);
        gload16(bL + wv * 2048 +        lane * 16, (char*)BsL[p] + wv * 2048);
        gload16(bL + wv * 2048 + 1024 + lane * 16, (char*)BsL[p] + wv * 2048 + 1024);
    };

    stage(0, 0);
    __syncthreads();

    for (int t = 0; t < nk; ++t) {
        const int p = t & 1;
        if (t + 1 < nk) stage(t + 1, p ^ 1);   // prefetch hides under MFMA
        mfma_core(AsH[p], AsL[p], BsH[p], BsL[p], wv, lr, lh, acc);
        __syncthreads();
    }

    epilogue_write(C, ldc, n0, wv, lr, lh, acc);
}

#define DECLARE_LDS4() \
    __shared__ alignas(16) unsigned short AsH[2][4096]; \
    __shared__ alignas(16) unsigned short AsL[2][4096]; \
    __shared__ alignas(16) unsigned short BsH[2][4096]; \
    __shared__ alignas(16) unsigned short BsL[2][4096];   /* 64 KiB */

// ---------------------------------------------------------------------------
// in_proj: part[ks][64][512] = hidden @ in_w^T.
// 128 blocks x 256 thr (8 nt2 x 16 ks), klen=256 (4 k-steps), NT=64.
// ---------------------------------------------------------------------------
__global__ __launch_bounds__(256) void k_inproj(
    const char* __restrict__ hidH, const char* __restrict__ hidL,
    const unsigned short* __restrict__ WH, const unsigned short* __restrict__ WL,
    float* __restrict__ part)
{
    DECLARE_LDS4();
    int nt2 = blockIdx.x & 7;                 // 0..7 (N-tile of 64)
    int ks  = blockIdx.x >> 3;                // 0..15
    size_t btile = (size_t)((nt2 >> 1) * 64 + ks * 4) * 8192 + (size_t)(nt2 & 1) * 4096;
    mfma_gemm4(hidH, hidL, 8192, ks * 256,
               WH, WL, btile, 4,
               part + ks * 32768, 512, nt2 * 64,
               AsH, AsL, BsH, BsL);
}

__global__ __launch_bounds__(256) void k_reduce_inproj(
    const float* __restrict__ part, const float* __restrict__ bias,
    float* __restrict__ hA, float* __restrict__ hB,
    unsigned short* hAH, unsigned short* hAL,
    unsigned short* hBH, unsigned short* hBL)
{
    int i = blockIdx.x * 256 + threadIdx.x;   // < 32768
    int b = i >> 9;
    int d = i & 511;
    float s = bias[d];
#pragma unroll
    for (int ks = 0; ks < 16; ++ks) s += part[ks * 32768 + i];
    hA[i] = s;
    hB[i] = s;
    store_plane(hAH, hAL, b, d, s);
    store_plane(hBH, hBL, b, d, s);
}

// ---------------------------------------------------------------------------
// Gates layer 0, K-split 4, NT=64: 192 blocks x 256 thr (24 nt2 x 4 ks x 2 mat).
//  mat1: gh0 = hA @ w_hh0^T (mfma_gemm4, unchanged geometry).
//  mat0: gi0 = x @ w_ih0^T with x FUSED: coalesced argmax over the 500
//        TRANSPOSED partials (hidden under B-stage drain) + embed gather +
//        split2 written directly into the 4-wave A-LDS layout. Identical
//        value path + MFMA order -> gi0 bitwise identical to R13.
//        Step 0: exact zero 64x64 tile.
// ---------------------------------------------------------------------------
__global__ __launch_bounds__(256) void k_gates_l0(
    int step,
    const float* __restrict__ pvT, const int* __restrict__ piT,
    const float* __restrict__ embed,
    const char* __restrict__ hAH, const char* __restrict__ hAL,
    const unsigned short* __restrict__ gwH, const unsigned short* __restrict__ gwL,
    float* __restrict__ gip, float* __restrict__ ghp)
{
    DECLARE_LDS4();
    __shared__ int stok[64];
    const int bx = blockIdx.x, tid = threadIdx.x;
    const int nt2 = bx % 24, ks = (bx / 24) & 3, mat = bx / 96;

    if (mat) {
        size_t btile = ((size_t)96 + (nt2 >> 1) * 8 + ks * 2) * 8192
                     + (size_t)(nt2 & 1) * 4096;             // w_hh0
        mfma_gemm4(hAH, hAL, 1024, ks * 128, gwH, gwL, btile, 2,
                   ghp + ks * 98304, 1536, nt2 * 64, AsH, AsL, BsH, BsL);
        return;
    }

    float* C = gip + ks * 98304;
    if (step == 0) {                           // x = 0 -> exact zero 64x64 tile
        float4 z = make_float4(0.f, 0.f, 0.f, 0.f);
        for (int q = tid; q < 1024; q += 256) {
            int r2 = q >> 4, cq = q & 15;
            *(float4*)(C + r2 * 1536 + nt2 * 64 + cq * 4) = z;
        }
        return;
    }

    const int wv = tid >> 6, lane = tid & 63, lr = lane & 15, lh = lane >> 4;
    const size_t btileU = ((size_t)((nt2 >> 1) * 8 + ks * 2)) * 8192
                        + (size_t)(nt2 & 1) * 4096;          // w_ih0
    auto stageB = [&](int t, int p) {
        const char* bH = (const char*)gwH + (btileU + (size_t)t * 8192) * 2;
        const char* bL = (const char*)gwL + (btileU + (size_t)t * 8192) * 2;
        gload16(bH + wv * 2048 +        lane * 16, (char*)BsH[p] + wv * 2048);
        gload16(bH + wv * 2048 + 1024 + lane * 16, (char*)BsH[p] + wv * 2048 + 1024);
        gload16(bL + wv * 2048 +        lane * 16, (char*)BsL[p] + wv * 2048);
        gload16(bL + wv * 2048 + 1024 + lane * 16, (char*)BsL[p] + wv * 2048 + 1024);
    };

    stageB(0, 0);                              // B(0) latency hides the scan

    // coalesced argmax over 500 transposed partials: 4 threads per batch row
    {
        int r = tid >> 2, j0 = tid & 3;
        float v = -3.4e38f; int c = 0x7fffffff;
        for (int j = j0; j < 500; j += 4) {
            float ov = pvT[r * 512 + j]; int oc = piT[r * 512 + j];
            if (ov > v || (ov == v && oc < c)) { v = ov; c = oc; }
        }
#pragma unroll
        for (int msk = 1; msk < 4; msk <<= 1) {
            float ov = __shfl_xor(v, msk, 64);
            int   oc = __shfl_xor(c, msk, 64);
            if (ov > v || (ov == v && oc < c)) { v = ov; c = oc; }
        }
        if (j0 == 0) stok[r] = c;
    }
    __syncthreads();                           // tokens ready (drains B(0) too)

    // x tiles (2 k-tiles of 64 cols): embed gather + split into 4-wave A-LDS
    // layout: row m chunk cl -> ushort off (m>>4)*1024 + (m&15)*64 + ((cl^(m&7))*8)
    {
        int mm = tid >> 2, cl0 = (tid & 3) * 2;
        int tok = stok[mm];
        int obase = (mm >> 4) * 1024 + (mm & 15) * 64;
#pragma unroll
        for (int t2 = 0; t2 < 2; ++t2) {
#pragma unroll
            for (int u = 0; u < 2; ++u) {
                int cl = cl0 + u;
                const float* src = embed + (size_t)tok * 512 + ks * 128 + t2 * 64 + cl * 8;
                float4 v0 = *(const float4*)src;
                float4 v1 = *(const float4*)(src + 4);
                unsigned short h[8], l[8];
                split2(v0.x,h[0],l[0]); split2(v0.y,h[1],l[1]); split2(v0.z,h[2],l[2]); split2(v0.w,h[3],l[3]);
                split2(v1.x,h[4],l[4]); split2(v1.y,h[5],l[5]); split2(v1.z,h[6],l[6]); split2(v1.w,h[7],l[7]);
                uint4 ph = make_uint4((unsigned)h[0]|((unsigned)h[1]<<16), (unsigned)h[2]|((unsigned)h[3]<<16),
                                      (unsigned)h[4]|((unsigned)h[5]<<16), (unsigned)h[6]|((unsigned)h[7]<<16));
                uint4 pl = make_uint4((unsigned)l[0]|((unsigned)l[1]<<16), (unsigned)l[2]|((unsigned)l[3]<<16),
                                      (unsigned)l[4]|((unsigned)l[5]<<16), (unsigned)l[6]|((unsigned)l[7]<<16));
                int off = obase + ((cl ^ (mm & 7)) * 8);
                *(uint4*)(AsH[t2] + off) = ph;
                *(uint4*)(AsL[t2] + off) = pl;
            }
        }
    }
    stageB(1, 1);
    __syncthreads();                           // x writes + B(1) drained

    f32x4 acc[4];
#pragma unroll
    for (int i = 0; i < 4; ++i) acc[i] = (f32x4){0.f, 0.f, 0.f, 0.f};
    mfma_core(AsH[0], AsL[0], BsH[0], BsL[0], wv, lr, lh, acc);
    mfma_core(AsH[1], AsL[1], BsH[1], BsL[1], wv, lr, lh, acc);
    epilogue_write(C, 1536, nt2 * 64, wv, lr, lh, acc);
}

// ---------------------------------------------------------------------------
// GRU gates layer 1, K-split 4, NT=64: 192 blocks (24 nt2 x 4 ks x 2 mat).
// mat0: gi1 = hA' @ w_ih1^T ; mat1: gh1 = hB @ w_hh1^T.
// ---------------------------------------------------------------------------
__global__ __launch_bounds__(256) void k_gates(
    const char* __restrict__ xH, const char* __restrict__ xL,
    const char* __restrict__ hH, const char* __restrict__ hL,
    const unsigned short* __restrict__ gwH, const unsigned short* __restrict__ gwL,
    int layer, float* __restrict__ gip, float* __restrict__ ghp)
{
    DECLARE_LDS4();
    int bx  = blockIdx.x;
    int nt2 = bx % 24;                        // 0..23 (N-tile of 64 over 1536)
    int ks  = (bx / 24) & 3;
    int mat = bx / 96;
    const char* AH = mat ? hH : xH;
    const char* AL = mat ? hL : xL;
    float* C = (mat ? ghp : gip) + ks * 98304;
    size_t btile = ((size_t)(layer * 2 + mat) * 96 + (nt2 >> 1) * 8 + ks * 2) * 8192
                 + (size_t)(nt2 & 1) * 4096;
    mfma_gemm4(AH, AL, 1024, ks * 128,
               gwH, gwL, btile, 2,
               C, 1536, nt2 * 64,
               AsH, AsL, BsH, BsL);
}

__global__ __launch_bounds__(256) void k_combine(
    const float* __restrict__ gip, const float* __restrict__ ghp,
    const float* __restrict__ b_ih, const float* __restrict__ b_hh,
    float* __restrict__ h, unsigned short* hH, unsigned short* hL)
{
    int i = blockIdx.x * 256 + threadIdx.x;   // < 32768
    int b = i >> 9;
    int d = i & 511;
    int base = b * 1536 + d;
    float ir = b_ih[d], iz = b_ih[d + 512], inn = b_ih[d + 1024];
    float hr = b_hh[d], hz = b_hh[d + 512], hn = b_hh[d + 1024];
#pragma unroll
    for (int ks = 0; ks < 4; ++ks) {
        const float* gi = gip + ks * 98304 + base;
        const float* gh = ghp + ks * 98304 + base;
        ir  += gi[0];    iz += gi[512];  inn += gi[1024];
        hr  += gh[0];    hz += gh[512];  hn  += gh[1024];
    }
    float r = 1.f / (1.f + expf(-(ir + hr)));
    float z = 1.f / (1.f + expf(-(iz + hz)));
    float n = tanhf(inn + r * hn);
    float hv = (1.f - z) * n + z * h[i];
    h[i] = hv;
    store_plane(hH, hL, b, d, hv);
}

// ---------------------------------------------------------------------------
// logits: 500 blocks x 256 threads (4 waves), NT=64, 64 KiB LDS ->
// 2 blocks/CU fully co-resident. B = out_w fp32 split in-register
// (issue-early/write-late); A = hB planes via 4-wave gload_lds identity.
// Argmax partials written TRANSPOSED: pvT[row*512 + blk].
// ---------------------------------------------------------------------------
__global__ __launch_bounds__(256) void k_logits(
    const char* __restrict__ hBH, const char* __restrict__ hBL,
    const float* __restrict__ out_w,
    float* __restrict__ out, int step,
    float* __restrict__ pvT, int* __restrict__ piT)
{
    __shared__ alignas(16) unsigned short AsH[2][4096];
    __shared__ alignas(16) unsigned short AsL[2][4096];
    __shared__ alignas(16) unsigned short BsH[2][4096];
    __shared__ alignas(16) unsigned short BsL[2][4096];    // 64 KiB

    const int tid  = threadIdx.x;
    const int wv   = tid >> 6;
    const int lane = tid & 63;
    const int lr   = lane & 15;
    const int lh   = lane >> 4;
    const int bx   = blockIdx.x;
    const int n0   = bx * 64;

    const int ar1 = wv * 16 + (lane >> 3);
    const int acp = lane & 7;
    auto stageA = [&](int kaB, int p) {
        gload16(hBH + ar1 * 1024 + kaB + acp * 16,       (char*)AsH[p] + wv * 2048);
        gload16(hBH + (ar1 + 8) * 1024 + kaB + acp * 16, (char*)AsH[p] + wv * 2048 + 1024);
        gload16(hBL + ar1 * 1024 + kaB + acp * 16,       (char*)AsL[p] + wv * 2048);
        gload16(hBL + (ar1 + 8) * 1024 + kaB + acp * 16, (char*)AsL[p] + wv * 2048 + 1024);
    };

    const int bn = tid >> 2, bq = tid & 3;
    const float* Wb = out_w + (size_t)(n0 + bn) * 512 + bq * 16;
    const int wo0 = bn * 64 + (((2 * bq)     ^ (bn & 7)) * 8);
    const int wo1 = bn * 64 + (((2 * bq + 1) ^ (bn & 7)) * 8);

    float4 r0, r1, r2, r3;
    auto loadB = [&](int t) {
        const float* s = Wb + t * 64;
        r0 = *(const float4*)s;       r1 = *(const float4*)(s + 4);
        r2 = *(const float4*)(s + 8); r3 = *(const float4*)(s + 12);
    };
    auto writeB = [&](int p) {
        unsigned short h[16], l[16];
        split2(r0.x,h[0],l[0]);   split2(r0.y,h[1],l[1]);   split2(r0.z,h[2],l[2]);   split2(r0.w,h[3],l[3]);
        split2(r1.x,h[4],l[4]);   split2(r1.y,h[5],l[5]);   split2(r1.z,h[6],l[6]);   split2(r1.w,h[7],l[7]);
        split2(r2.x,h[8],l[8]);   split2(r2.y,h[9],l[9]);   split2(r2.z,h[10],l[10]); split2(r2.w,h[11],l[11]);
        split2(r3.x,h[12],l[12]); split2(r3.y,h[13],l[13]); split2(r3.z,h[14],l[14]); split2(r3.w,h[15],l[15]);
        *(uint4*)(BsH[p] + wo0) = make_uint4(
            (unsigned)h[0]|((unsigned)h[1]<<16),  (unsigned)h[2]|((unsigned)h[3]<<16),
            (unsigned)h[4]|((unsigned)h[5]<<16),  (unsigned)h[6]|((unsigned)h[7]<<16));
        *(uint4*)(BsH[p] + wo1) = make_uint4(
            (unsigned)h[8]|((unsigned)h[9]<<16),  (unsigned)h[10]|((unsigned)h[11]<<16),
            (unsigned)h[12]|((unsigned)h[13]<<16),(unsigned)h[14]|((unsigned)h[15]<<16));
        *(uint4*)(BsL[p] + wo0) = make_uint4(
            (unsigned)l[0]|((unsigned)l[1]<<16),  (unsigned)l[2]|((unsigned)l[3]<<16),
            (unsigned)l[4]|((unsigned)l[5]<<16),  (unsigned)l[6]|((unsigned)l[7]<<16));
        *(uint4*)(BsL[p] + wo1) = make_uint4(
            (unsigned)l[8]|((unsigned)l[9]<<16),  (unsigned)l[10]|((unsigned)l[11]<<16),
            (unsigned)l[12]|((unsigned)l[13]<<16),(unsigned)l[14]|((unsigned)l[15]<<16));
    };

    f32x4 acc[4];
#pragma unroll
    for (int i = 0; i < 4; ++i) acc[i] = (f32x4){0.f, 0.f, 0.f, 0.f};

    loadB(0);
    stageA(0, 0);
    writeB(0);
    __syncthreads();
#pragma unroll
    for (int t = 0; t < 8; ++t) {
        const int p = t & 1;
        if (t < 7) { loadB(t + 1); stageA((t + 1) * 128, p ^ 1); }
        mfma_core(AsH[p], AsL[p], BsH[p], BsL[p], wv, lr, lh, acc);
        if (t < 7) writeB(p ^ 1);              // into the other buffer
        __syncthreads();
    }

    epilogue_write(out + step * 32000, 128000, n0, wv, lr, lh, acc);

    // ---- per-block argmax partials (transposed layout) ----
    float* sv = (float*)&AsH[0][0];            // 256 floats
    int*   sc = (int*)&AsL[0][0];
#pragma unroll
    for (int mt = 0; mt < 4; ++mt)
#pragma unroll
        for (int i = 0; i < 4; ++i) {
            float v = acc[mt][i];
            int   c = n0 + wv * 16 + lr;
#pragma unroll
            for (int msk = 1; msk < 16; msk <<= 1) {
                float ov = __shfl_xor(v, msk, 64);
                int   oc = __shfl_xor(c, msk, 64);
                if (ov > v || (ov == v && oc < c)) { v = ov; c = oc; }
            }
            if (lr == 0) {
                int row = mt * 16 + lh * 4 + i;
                sv[wv * 64 + row] = v;
                sc[wv * 64 + row] = c;
            }
        }
    __syncthreads();
    if (tid < 64) {
        float v = sv[tid]; int c = sc[tid];
#pragma unroll
        for (int w = 1; w < 4; ++w) {
            float ov = sv[w * 64 + tid]; int oc = sc[w * 64 + tid];
            if (ov > v || (ov == v && oc < c)) { v = ov; c = oc; }
        }
        pvT[tid * 512 + bx] = v;
        piT[tid * 512 + bx] = c;
    }
}

// ---------------------------------------------------------------------------
extern "C" void kernel_launch(void* const* d_in, const int* in_sizes, int n_in,
                              void* d_out, int out_size, void* d_ws, size_t ws_size,
                              hipStream_t stream)
{
    const float* hidden = (const float*)d_in[0];
    const float* in_w   = (const float*)d_in[1];
    const float* in_b   = (const float*)d_in[2];
    const float* w_ih0  = (const float*)d_in[3];
    const float* w_hh0  = (const float*)d_in[4];
    const float* b_ih0  = (const float*)d_in[5];
    const float* b_hh0  = (const float*)d_in[6];
    const float* w_ih1  = (const float*)d_in[7];
    const float* w_hh1  = (const float*)d_in[8];
    const float* b_ih1  = (const float*)d_in[9];
    const float* b_hh1  = (const float*)d_in[10];
    const float* embed  = (const float*)d_in[11];
    const float* out_w  = (const float*)d_in[12];
    float* out = (float*)d_out;                    // [64, 4, 32000]
    char*  ws  = (char*)d_ws;

    // ws layout (bytes) — ~28 MiB, all L3-resident
    float* hA  = (float*)(ws + 0);                 // 131072
    float* hB  = (float*)(ws + 131072);            // 131072
    unsigned short* hAH = (unsigned short*)(ws + 393216);   // 65536 each
    unsigned short* hAL = (unsigned short*)(ws + 458752);
    unsigned short* hBH = (unsigned short*)(ws + 524288);
    unsigned short* hBL = (unsigned short*)(ws + 589824);
    char* hidH = ws + 655360;                      // 524288
    char* hidL = ws + 1179648;                     // 524288
    float* gip = (float*)(ws + 1703936);           // 4*98304 fl = 1572864 B
    float* ghp = (float*)(ws + 3276800);           // 1572864 B
    float* pvT = (float*)(ws + 4849664);           // 64*512*4 = 131072
    int*   piT = (int*)  (ws + 4980736);           // 131072
    float* ipart = (float*)(ws + 5111808);         // 16*32768 fl = 2097152 B
    unsigned short* gwH = (unsigned short*)(ws + 7208960);   // 6291456
    unsigned short* gwL = (unsigned short*)(ws + 13500416);  // 6291456
    unsigned short* inH = (unsigned short*)(ws + 19791872);  // 4194304
    unsigned short* inL = (unsigned short*)(ws + 23986176);  // 4194304

    // ---- prologue: 5 dispatches ----
    k_split_A<<<128, 256, 0, stream>>>(hidden, hidH, hidL);
    k_split_gw<<<dim3(384, 4), 256, 0, stream>>>(w_ih0, w_hh0, w_ih1, w_hh1, gwH, gwL);
    k_split_W<<<1024, 256, 0, stream>>>(in_w, inH, inL, 9);            // 512x4096
    k_inproj<<<128, 256, 0, stream>>>(hidH, hidL, inH, inL, ipart);
    k_reduce_inproj<<<128, 256, 0, stream>>>(ipart, in_b, hA, hB,
                                             hAH, hAL, hBH, hBL);

    // ---- step loop: 5 dispatches/step ----
    for (int step = 0; step < 4; ++step) {
        k_gates_l0<<<192, 256, 0, stream>>>(step, pvT, piT, embed,
                                            (char*)hAH, (char*)hAL,
                                            gwH, gwL, gip, ghp);
        k_combine<<<128, 256, 0, stream>>>(gip, ghp, b_ih0, b_hh0, hA, hAH, hAL);
        k_gates<<<192, 256, 0, stream>>>((char*)hAH, (char*)hAL, (char*)hBH, (char*)hBL,
                                         gwH, gwL, 1, gip, ghp);
        k_combine<<<128, 256, 0, stream>>>(gip, ghp, b_ih1, b_hh1, hB, hBH, hBL);
        k_logits<<<500, 256, 0, stream>>>((char*)hBH, (char*)hBL, out_w,
                                          out, step, pvT, piT);
    }
}

// Round 11
// 352.152 us; speedup vs baseline: 1.1136x; 1.1136x over previous
//
#include <hip/hip_runtime.h>
#include <math.h>

// ReDrafterHead: B=64, H=4096, D=512, G3=1536, V=32000, STEPS=4
// Round 15 = Round 13 verbatim (354.3us, session best). R14's coalesced
// fused-argmax regressed identically to R12's strided one (+38us) ->
// fusion mechanism falsified (serial pre-MFMA argmax+cold-embed-gather in
// 96 blocks costs ~10us/step vs ~6us of launches saved). All structural
// fusions tried this session (cooperative R6, merge R7/R12, fused R14)
// lost to dedicated small kernels. Locking in the validated optimum:
// 4-wave/NT=64/64KiB GEMMs (2 blocks/CU), no out_w pre-split, in-kernel
// fp32 B-split for logits, dedicated reduce_embed.

typedef __attribute__((ext_vector_type(8))) short short8;   // 8 bf16
typedef __attribute__((ext_vector_type(4))) float f32x4;

__device__ __forceinline__ unsigned short f2bf_rne(float x) {
    unsigned u = __float_as_uint(x);
    unsigned r = (u + 0x7fffu + ((u >> 16) & 1u)) >> 16;
    return (unsigned short)r;
}
// hi = truncate; lo = RNE of residual. 3-pass MFMA error ~2^-16 rel.
__device__ __forceinline__ void split2(float x, unsigned short& hi, unsigned short& lo) {
    unsigned u = __float_as_uint(x);
    hi = (unsigned short)(u >> 16);
    float r = x - __uint_as_float(u & 0xffff0000u);
    lo = f2bf_rne(r);
}

// store one element into swizzled bf16 hi/lo planes, row stride 512 elems.
__device__ __forceinline__ void store_plane(unsigned short* hiP, unsigned short* loP,
                                            int m, int d, float v) {
    int s = d >> 6, cl = (d >> 3) & 7, e = d & 7;
    int off = m * 512 + s * 64 + ((cl ^ (m & 7)) * 8) + e;
    unsigned short hi, lo; split2(v, hi, lo);
    hiP[off] = hi; loP[off] = lo;
}

__device__ __forceinline__ void gload16(const void* g, void* lds) {
    __builtin_amdgcn_global_load_lds(
        (const __attribute__((address_space(1))) unsigned int*)g,
        (__attribute__((address_space(3))) unsigned int*)lds, 16, 0, 0);
}

// ---------------------------------------------------------------------------
// Weight pre-split: W[N][K] fp32 -> swizzled bf16 planes, tile-major:
// ushort off = ((nt*(K/64) + ks)*128 + row)*64 + ((c8&7)^(row&7))*8
// ---------------------------------------------------------------------------
__device__ __forceinline__ void split_w_body(
    const float* __restrict__ W, unsigned short* __restrict__ H,
    unsigned short* __restrict__ L, size_t g, int kclog)
{
    int n  = (int)(g >> kclog);
    int c8 = (int)g & ((1 << kclog) - 1);
    const float* src = W + g * 8;
    float4 v0 = *(const float4*)src;
    float4 v1 = *(const float4*)(src + 4);
    unsigned short h[8], l[8];
    split2(v0.x,h[0],l[0]); split2(v0.y,h[1],l[1]); split2(v0.z,h[2],l[2]); split2(v0.w,h[3],l[3]);
    split2(v1.x,h[4],l[4]); split2(v1.y,h[5],l[5]); split2(v1.z,h[6],l[6]); split2(v1.w,h[7],l[7]);
    uint4 ph = make_uint4((unsigned)h[0]|((unsigned)h[1]<<16), (unsigned)h[2]|((unsigned)h[3]<<16),
                          (unsigned)h[4]|((unsigned)h[5]<<16), (unsigned)h[6]|((unsigned)h[7]<<16));
    uint4 pl = make_uint4((unsigned)l[0]|((unsigned)l[1]<<16), (unsigned)l[2]|((unsigned)l[3]<<16),
                          (unsigned)l[4]|((unsigned)l[5]<<16), (unsigned)l[6]|((unsigned)l[7]<<16));
    int nt = n >> 7, row = n & 127;
    int ksi = c8 >> 3;
    int slot = (c8 & 7) ^ (row & 7);
    int tpr = 1 << (kclog - 3);                 // tiles per row-tile = K/64
    size_t off = ((size_t)(nt * tpr + ksi) * 128 + row) * 64 + slot * 8;
    *(uint4*)(H + off) = ph;
    *(uint4*)(L + off) = pl;
}

__global__ __launch_bounds__(256) void k_split_W(
    const float* __restrict__ W, unsigned short* __restrict__ H,
    unsigned short* __restrict__ L, int kclog)
{
    size_t g = (size_t)blockIdx.x * 256 + threadIdx.x;
    split_w_body(W, H, L, g, kclog);
}

// 4 GRU weight matrices in one launch: grid (384, 4), blockIdx.y picks mat.
__global__ __launch_bounds__(256) void k_split_gw(
    const float* __restrict__ w0, const float* __restrict__ w1,
    const float* __restrict__ w2, const float* __restrict__ w3,
    unsigned short* __restrict__ H, unsigned short* __restrict__ L)
{
    int mat = blockIdx.y;
    const float* W = mat == 0 ? w0 : mat == 1 ? w1 : mat == 2 ? w2 : w3;
    size_t g = (size_t)blockIdx.x * 256 + threadIdx.x;     // < 98304
    split_w_body(W, H + (size_t)mat * 786432, L + (size_t)mat * 786432, g, 6);
}

// ---------------------------------------------------------------------------
// split hidden[64,4096] fp32 -> swizzled bf16 planes (row stride 8192 B)
// ---------------------------------------------------------------------------
__global__ __launch_bounds__(256) void k_split_A(
    const float* __restrict__ hidden, char* __restrict__ hidH, char* __restrict__ hidL)
{
    int g = blockIdx.x * 256 + threadIdx.x;   // 32768 chunks
    int m = g >> 9;
    int cc = g & 511;
    int s = cc >> 3, cl = cc & 7;
    const float* src = hidden + m * 4096 + cc * 8;
    float4 v0 = *(const float4*)src;
    float4 v1 = *(const float4*)(src + 4);
    unsigned short h[8], l[8];
    split2(v0.x,h[0],l[0]); split2(v0.y,h[1],l[1]); split2(v0.z,h[2],l[2]); split2(v0.w,h[3],l[3]);
    split2(v1.x,h[4],l[4]); split2(v1.y,h[5],l[5]); split2(v1.z,h[6],l[6]); split2(v1.w,h[7],l[7]);
    uint4 ph = make_uint4((unsigned)h[0]|((unsigned)h[1]<<16), (unsigned)h[2]|((unsigned)h[3]<<16),
                          (unsigned)h[4]|((unsigned)h[5]<<16), (unsigned)h[6]|((unsigned)h[7]<<16));
    uint4 pl = make_uint4((unsigned)l[0]|((unsigned)l[1]<<16), (unsigned)l[2]|((unsigned)l[3]<<16),
                          (unsigned)l[4]|((unsigned)l[5]<<16), (unsigned)l[6]|((unsigned)l[7]<<16));
    int off = m * 8192 + s * 128 + ((cl ^ (m & 7)) * 16);
    *(uint4*)(hidH + off) = ph;
    *(uint4*)(hidL + off) = pl;
}

// ---------------------------------------------------------------------------
// Shared MFMA inner core: one 64-k tile from LDS buffers into acc[4].
// Works for 4-wave (brow 0..63) and logits layouts.
// ---------------------------------------------------------------------------
__device__ __forceinline__ void mfma_core(
    const unsigned short* __restrict__ AsH0, const unsigned short* __restrict__ AsL0,
    const unsigned short* __restrict__ BsH0, const unsigned short* __restrict__ BsL0,
    int wv, int lr, int lh, f32x4* acc)
{
#pragma unroll
    for (int kk2 = 0; kk2 < 2; ++kk2) {
        int aoff = lr * 64 + (((kk2 * 4 + lh) ^ (lr & 7)) * 8);
        short8 ah[4], al[4];
#pragma unroll
        for (int mt = 0; mt < 4; ++mt) {
            ah[mt] = *(const short8*)(AsH0 + mt * 1024 + aoff);
            al[mt] = *(const short8*)(AsL0 + mt * 1024 + aoff);
        }
        int brow = wv * 16 + lr;
        int boff = brow * 64 + (((kk2 * 4 + lh) ^ (brow & 7)) * 8);
        short8 bh = *(const short8*)(BsH0 + boff);
        short8 bl = *(const short8*)(BsL0 + boff);
#pragma unroll
        for (int mt = 0; mt < 4; ++mt) {
            acc[mt] = __builtin_amdgcn_mfma_f32_16x16x32_bf16(ah[mt], bh, acc[mt], 0, 0, 0);
            acc[mt] = __builtin_amdgcn_mfma_f32_16x16x32_bf16(ah[mt], bl, acc[mt], 0, 0, 0);
            acc[mt] = __builtin_amdgcn_mfma_f32_16x16x32_bf16(al[mt], bh, acc[mt], 0, 0, 0);
        }
    }
}

__device__ __forceinline__ void epilogue_write(
    float* __restrict__ C, int ldc, int n0, int wv, int lr, int lh, const f32x4* acc)
{
#pragma unroll
    for (int mt = 0; mt < 4; ++mt)
#pragma unroll
        for (int i = 0; i < 4; ++i) {
            int mm = mt * 16 + lh * 4 + i;
            C[mm * ldc + n0 + wv * 16 + lr] = acc[mt][i];
        }
}

// ---------------------------------------------------------------------------
// 4-wave plane GEMM (256 threads), NT=64, 64 KiB LDS -> 2 blocks/CU.
// C[0..63][n0..n0+63] over nk k-steps. A: swizzled planes (stride AstrideB,
// start col akk0). B: tiled planes; btileU already includes the half-tile
// offset (rows [0,64) of the 64-col N-slice).
// ---------------------------------------------------------------------------
__device__ __forceinline__ void mfma_gemm4(
    const char* __restrict__ AH, const char* __restrict__ AL, int AstrideB, int akk0,
    const unsigned short* __restrict__ BH, const unsigned short* __restrict__ BL,
    size_t btileU, int nk,
    float* __restrict__ C, int ldc, int n0,
    unsigned short (*AsH)[4096], unsigned short (*AsL)[4096],
    unsigned short (*BsH)[4096], unsigned short (*BsL)[4096])
{
    const int tid  = threadIdx.x;
    const int wv   = tid >> 6;
    const int lane = tid & 63;
    const int lr   = lane & 15;
    const int lh   = lane >> 4;
    const int ar1  = wv * 16 + (lane >> 3);   // A staging row (call 1)
    const int acp  = lane & 7;                // A staging chunk

    f32x4 acc[4];
#pragma unroll
    for (int i = 0; i < 4; ++i) acc[i] = (f32x4){0.f, 0.f, 0.f, 0.f};

    auto stage = [&](int t, int p) {
        const int kaB = (akk0 + t * 64) * 2;
        gload16(AH + ar1 * AstrideB + kaB + acp * 16,       (char*)AsH[p] + wv * 2048);
        gload16(AH + (ar1 + 8) * AstrideB + kaB + acp * 16, (char*)AsH[p] + wv * 2048 + 1024);
        gload16(AL + ar1 * AstrideB + kaB + acp * 16,       (char*)AsL[p] + wv * 2048);
        gload16(AL + (ar1 + 8) * AstrideB + kaB + acp * 16, (char*)AsL[p] + wv * 2048 + 1024);
        const char* bH = (const char*)BH + (btileU + (size_t)t * 8192) * 2;
        const char* bL = (const char*)BL + (btileU + (size_t)t * 8192) * 2;
        gload16(bH + wv * 2048 +        lane * 16, (char*)BsH[p] + wv * 2048);
        gload16(bH + wv * 2048 + 1024 + lane * 16, (char*)BsH[p] + wv * 2048 + 1024);
        gload16(bL + wv * 2048 +        lane * 16, (char*)BsL[p] + wv * 2048);
        gload16(bL + wv * 2048 + 1024 + lane * 16, (char*)BsL[p] + wv * 2048 + 1024);
    };

    stage(0, 0);
    __syncthreads();

    for (int t = 0; t < nk; ++t) {
        const int p = t & 1;
        if (t + 1 < nk) stage(t + 1, p ^ 1);   // prefetch hides under MFMA
        mfma_core(AsH[p], AsL[p], BsH[p], BsL[p], wv, lr, lh, acc);
        __syncthreads();
    }

    epilogue_write(C, ldc, n0, wv, lr, lh, acc);
}

#define DECLARE_LDS4() \
    __shared__ alignas(16) unsigned short AsH[2][4096]; \
    __shared__ alignas(16) unsigned short AsL[2][4096]; \
    __shared__ alignas(16) unsigned short BsH[2][4096]; \
    __shared__ alignas(16) unsigned short BsL[2][4096];   /* 64 KiB */

// ---------------------------------------------------------------------------
// in_proj: part[ks][64][512] = hidden @ in_w^T.
// 128 blocks x 256 thr (8 nt2 x 16 ks), klen=256 (4 k-steps), NT=64.
// ---------------------------------------------------------------------------
__global__ __launch_bounds__(256) void k_inproj(
    const char* __restrict__ hidH, const char* __restrict__ hidL,
    const unsigned short* __restrict__ WH, const unsigned short* __restrict__ WL,
    float* __restrict__ part)
{
    DECLARE_LDS4();
    int nt2 = blockIdx.x & 7;                 // 0..7 (N-tile of 64)
    int ks  = blockIdx.x >> 3;                // 0..15
    size_t btile = (size_t)((nt2 >> 1) * 64 + ks * 4) * 8192 + (size_t)(nt2 & 1) * 4096;
    mfma_gemm4(hidH, hidL, 8192, ks * 256,
               WH, WL, btile, 4,
               part + ks * 32768, 512, nt2 * 64,
               AsH, AsL, BsH, BsL);
}

__global__ __launch_bounds__(256) void k_reduce_inproj(
    const float* __restrict__ part, const float* __restrict__ bias,
    float* __restrict__ hA, float* __restrict__ hB,
    unsigned short* hAH, unsigned short* hAL,
    unsigned short* hBH, unsigned short* hBL,
    unsigned short* xH,  unsigned short* xL)
{
    int i = blockIdx.x * 256 + threadIdx.x;   // < 32768
    int b = i >> 9;
    int d = i & 511;
    float s = bias[d];
#pragma unroll
    for (int ks = 0; ks < 16; ++ks) s += part[ks * 32768 + i];
    hA[i] = s;
    hB[i] = s;
    store_plane(hAH, hAL, b, d, s);
    store_plane(hBH, hBL, b, d, s);
    store_plane(xH,  xL,  b, d, 0.f);
}

// ---------------------------------------------------------------------------
// GRU gates, K-split 4, NT=64: 192 blocks x 256 thr (24 nt2 x 4 ks x 2 mat),
// klen=128 (2 k-steps). gw planes packed [w_ih0, w_hh0, w_ih1, w_hh1].
// ---------------------------------------------------------------------------
__global__ __launch_bounds__(256) void k_gates(
    const char* __restrict__ xH, const char* __restrict__ xL,
    const char* __restrict__ hH, const char* __restrict__ hL,
    const unsigned short* __restrict__ gwH, const unsigned short* __restrict__ gwL,
    int layer, float* __restrict__ gip, float* __restrict__ ghp)
{
    DECLARE_LDS4();
    int bx  = blockIdx.x;
    int nt2 = bx % 24;                        // 0..23 (N-tile of 64 over 1536)
    int ks  = (bx / 24) & 3;
    int mat = bx / 96;
    const char* AH = mat ? hH : xH;
    const char* AL = mat ? hL : xL;
    float* C = (mat ? ghp : gip) + ks * 98304;
    size_t btile = ((size_t)(layer * 2 + mat) * 96 + (nt2 >> 1) * 8 + ks * 2) * 8192
                 + (size_t)(nt2 & 1) * 4096;
    mfma_gemm4(AH, AL, 1024, ks * 128,
               gwH, gwL, btile, 2,
               C, 1536, nt2 * 64,
               AsH, AsL, BsH, BsL);
}

__global__ __launch_bounds__(256) void k_combine(
    const float* __restrict__ gip, const float* __restrict__ ghp,
    const float* __restrict__ b_ih, const float* __restrict__ b_hh,
    float* __restrict__ h, unsigned short* hH, unsigned short* hL)
{
    int i = blockIdx.x * 256 + threadIdx.x;   // < 32768
    int b = i >> 9;
    int d = i & 511;
    int base = b * 1536 + d;
    float ir = b_ih[d], iz = b_ih[d + 512], inn = b_ih[d + 1024];
    float hr = b_hh[d], hz = b_hh[d + 512], hn = b_hh[d + 1024];
#pragma unroll
    for (int ks = 0; ks < 4; ++ks) {
        const float* gi = gip + ks * 98304 + base;
        const float* gh = ghp + ks * 98304 + base;
        ir  += gi[0];    iz += gi[512];  inn += gi[1024];
        hr  += gh[0];    hz += gh[512];  hn  += gh[1024];
    }
    float r = 1.f / (1.f + expf(-(ir + hr)));
    float z = 1.f / (1.f + expf(-(iz + hz)));
    float n = tanhf(inn + r * hn);
    float hv = (1.f - z) * n + z * h[i];
    h[i] = hv;
    store_plane(hH, hL, b, d, hv);
}

// ---------------------------------------------------------------------------
// logits: 500 blocks x 256 threads (4 waves), NT=64, 64 KiB LDS ->
// 2 blocks/CU fully co-resident. B = out_w fp32 split in-register
// (issue-early/write-late); A = hB planes via 4-wave gload_lds identity.
// Per-block argmax partials pval/pidx.
// ---------------------------------------------------------------------------
__global__ __launch_bounds__(256) void k_logits(
    const char* __restrict__ hBH, const char* __restrict__ hBL,
    const float* __restrict__ out_w,
    float* __restrict__ out, int step,
    float* __restrict__ pval, int* __restrict__ pidx)
{
    __shared__ alignas(16) unsigned short AsH[2][4096];
    __shared__ alignas(16) unsigned short AsL[2][4096];
    __shared__ alignas(16) unsigned short BsH[2][4096];
    __shared__ alignas(16) unsigned short BsL[2][4096];    // 64 KiB

    const int tid  = threadIdx.x;
    const int wv   = tid >> 6;
    const int lane = tid & 63;
    const int lr   = lane & 15;
    const int lh   = lane >> 4;
    const int bx   = blockIdx.x;
    const int n0   = bx * 64;

    const int ar1 = wv * 16 + (lane >> 3);
    const int acp = lane & 7;
    auto stageA = [&](int kaB, int p) {
        gload16(hBH + ar1 * 1024 + kaB + acp * 16,       (char*)AsH[p] + wv * 2048);
        gload16(hBH + (ar1 + 8) * 1024 + kaB + acp * 16, (char*)AsH[p] + wv * 2048 + 1024);
        gload16(hBL + ar1 * 1024 + kaB + acp * 16,       (char*)AsL[p] + wv * 2048);
        gload16(hBL + (ar1 + 8) * 1024 + kaB + acp * 16, (char*)AsL[p] + wv * 2048 + 1024);
    };

    const int bn = tid >> 2, bq = tid & 3;
    const float* Wb = out_w + (size_t)(n0 + bn) * 512 + bq * 16;
    const int wo0 = bn * 64 + (((2 * bq)     ^ (bn & 7)) * 8);
    const int wo1 = bn * 64 + (((2 * bq + 1) ^ (bn & 7)) * 8);

    float4 r0, r1, r2, r3;
    auto loadB = [&](int t) {
        const float* s = Wb + t * 64;
        r0 = *(const float4*)s;       r1 = *(const float4*)(s + 4);
        r2 = *(const float4*)(s + 8); r3 = *(const float4*)(s + 12);
    };
    auto writeB = [&](int p) {
        unsigned short h[16], l[16];
        split2(r0.x,h[0],l[0]);   split2(r0.y,h[1],l[1]);   split2(r0.z,h[2],l[2]);   split2(r0.w,h[3],l[3]);
        split2(r1.x,h[4],l[4]);   split2(r1.y,h[5],l[5]);   split2(r1.z,h[6],l[6]);   split2(r1.w,h[7],l[7]);
        split2(r2.x,h[8],l[8]);   split2(r2.y,h[9],l[9]);   split2(r2.z,h[10],l[10]); split2(r2.w,h[11],l[11]);
        split2(r3.x,h[12],l[12]); split2(r3.y,h[13],l[13]); split2(r3.z,h[14],l[14]); split2(r3.w,h[15],l[15]);
        *(uint4*)(BsH[p] + wo0) = make_uint4(
            (unsigned)h[0]|((unsigned)h[1]<<16),  (unsigned)h[2]|((unsigned)h[3]<<16),
            (unsigned)h[4]|((unsigned)h[5]<<16),  (unsigned)h[6]|((unsigned)h[7]<<16));
        *(uint4*)(BsH[p] + wo1) = make_uint4(
            (unsigned)h[8]|((unsigned)h[9]<<16),  (unsigned)h[10]|((unsigned)h[11]<<16),
            (unsigned)h[12]|((unsigned)h[13]<<16),(unsigned)h[14]|((unsigned)h[15]<<16));
        *(uint4*)(BsL[p] + wo0) = make_uint4(
            (unsigned)l[0]|((unsigned)l[1]<<16),  (unsigned)l[2]|((unsigned)l[3]<<16),
            (unsigned)l[4]|((unsigned)l[5]<<16),  (unsigned)l[6]|((unsigned)l[7]<<16));
        *(uint4*)(BsL[p] + wo1) = make_uint4(
            (unsigned)l[8]|((unsigned)l[9]<<16),  (unsigned)l[10]|((unsigned)l[11]<<16),
            (unsigned)l[12]|((unsigned)l[13]<<16),(unsigned)l[14]|((unsigned)l[15]<<16));
    };

    f32x4 acc[4];
#pragma unroll
    for (int i = 0; i < 4; ++i) acc[i] = (f32x4){0.f, 0.f, 0.f, 0.f};

    loadB(0);
    stageA(0, 0);
    writeB(0);
    __syncthreads();
#pragma unroll
    for (int t = 0; t < 8; ++t) {
        const int p = t & 1;
        if (t < 7) { loadB(t + 1); stageA((t + 1) * 128, p ^ 1); }
        mfma_core(AsH[p], AsL[p], BsH[p], BsL[p], wv, lr, lh, acc);
        if (t < 7) writeB(p ^ 1);              // into the other buffer
        __syncthreads();
    }

    epilogue_write(out + step * 32000, 128000, n0, wv, lr, lh, acc);

    // ---- per-block argmax partials ----
    float* sv = (float*)&AsH[0][0];            // 256 floats
    int*   sc = (int*)&AsL[0][0];
#pragma unroll
    for (int mt = 0; mt < 4; ++mt)
#pragma unroll
        for (int i = 0; i < 4; ++i) {
            float v = acc[mt][i];
            int   c = n0 + wv * 16 + lr;
#pragma unroll
            for (int msk = 1; msk < 16; msk <<= 1) {
                float ov = __shfl_xor(v, msk, 64);
                int   oc = __shfl_xor(c, msk, 64);
                if (ov > v || (ov == v && oc < c)) { v = ov; c = oc; }
            }
            if (lr == 0) {
                int row = mt * 16 + lh * 4 + i;
                sv[wv * 64 + row] = v;
                sc[wv * 64 + row] = c;
            }
        }
    __syncthreads();
    if (tid < 64) {
        float v = sv[tid]; int c = sc[tid];
#pragma unroll
        for (int w = 1; w < 4; ++w) {
            float ov = sv[w * 64 + tid]; int oc = sc[w * 64 + tid];
            if (ov > v || (ov == v && oc < c)) { v = ov; c = oc; }
        }
        pval[bx * 64 + tid] = v;
        pidx[bx * 64 + tid] = c;
    }
}

// ---------------------------------------------------------------------------
// reduce 500 argmax partials (np first-occurrence) + embed gather -> x planes
// ---------------------------------------------------------------------------
__global__ __launch_bounds__(256) void k_reduce_embed(
    const float* __restrict__ pval, const int* __restrict__ pidx,
    const float* __restrict__ embed, unsigned short* xH, unsigned short* xL)
{
    __shared__ float sv[256];
    __shared__ int   sc[256];
    const int b = blockIdx.x;
    const int tid = threadIdx.x;
    float v = pval[tid * 64 + b];              // tid < 256 <= 500
    int   c = pidx[tid * 64 + b];
    if (tid + 256 < 500) {
        float ov = pval[(tid + 256) * 64 + b];
        int   oc = pidx[(tid + 256) * 64 + b];
        if (ov > v || (ov == v && oc < c)) { v = ov; c = oc; }
    }
    sv[tid] = v; sc[tid] = c;
    __syncthreads();
    for (int s = 128; s > 0; s >>= 1) {
        if (tid < s) {
            float ov = sv[tid + s]; int oc = sc[tid + s];
            if (ov > sv[tid] || (ov == sv[tid] && oc < sc[tid])) { sv[tid] = ov; sc[tid] = oc; }
        }
        __syncthreads();
    }
    int tok = sc[0];
    for (int j = tid; j < 512; j += 256)
        store_plane(xH, xL, b, j, embed[(size_t)tok * 512 + j]);
}

// ---------------------------------------------------------------------------
extern "C" void kernel_launch(void* const* d_in, const int* in_sizes, int n_in,
                              void* d_out, int out_size, void* d_ws, size_t ws_size,
                              hipStream_t stream)
{
    const float* hidden = (const float*)d_in[0];
    const float* in_w   = (const float*)d_in[1];
    const float* in_b   = (const float*)d_in[2];
    const float* w_ih0  = (const float*)d_in[3];
    const float* w_hh0  = (const float*)d_in[4];
    const float* b_ih0  = (const float*)d_in[5];
    const float* b_hh0  = (const float*)d_in[6];
    const float* w_ih1  = (const float*)d_in[7];
    const float* w_hh1  = (const float*)d_in[8];
    const float* b_ih1  = (const float*)d_in[9];
    const float* b_hh1  = (const float*)d_in[10];
    const float* embed  = (const float*)d_in[11];
    const float* out_w  = (const float*)d_in[12];
    float* out = (float*)d_out;                    // [64, 4, 32000]
    char*  ws  = (char*)d_ws;

    // ws layout (bytes) — ~28 MiB, all L3-resident
    float* hA  = (float*)(ws + 0);                 // 131072
    float* hB  = (float*)(ws + 131072);            // 131072
    unsigned short* xH  = (unsigned short*)(ws + 262144);   // 65536 each
    unsigned short* xL  = (unsigned short*)(ws + 327680);
    unsigned short* hAH = (unsigned short*)(ws + 393216);
    unsigned short* hAL = (unsigned short*)(ws + 458752);
    unsigned short* hBH = (unsigned short*)(ws + 524288);
    unsigned short* hBL = (unsigned short*)(ws + 589824);
    char* hidH = ws + 655360;                      // 524288
    char* hidL = ws + 1179648;                     // 524288
    float* gip = (float*)(ws + 1703936);           // 4*98304 fl = 1572864 B
    float* ghp = (float*)(ws + 3276800);           // 1572864 B
    float* pval = (float*)(ws + 4849664);          // 128000 (pad 131072)
    int*   pidx = (int*)  (ws + 4980736);          // 128000 (pad 131072)
    float* ipart = (float*)(ws + 5111808);         // 16*32768 fl = 2097152 B
    unsigned short* gwH = (unsigned short*)(ws + 7208960);   // 6291456
    unsigned short* gwL = (unsigned short*)(ws + 13500416);  // 6291456
    unsigned short* inH = (unsigned short*)(ws + 19791872);  // 4194304
    unsigned short* inL = (unsigned short*)(ws + 23986176);  // 4194304

    // ---- prologue: 5 dispatches (no out_w split) ----
    k_split_A<<<128, 256, 0, stream>>>(hidden, hidH, hidL);
    k_split_gw<<<dim3(384, 4), 256, 0, stream>>>(w_ih0, w_hh0, w_ih1, w_hh1, gwH, gwL);
    k_split_W<<<1024, 256, 0, stream>>>(in_w, inH, inL, 9);            // 512x4096
    k_inproj<<<128, 256, 0, stream>>>(hidH, hidL, inH, inL, ipart);
    k_reduce_inproj<<<128, 256, 0, stream>>>(ipart, in_b, hA, hB,
                                             hAH, hAL, hBH, hBL, xH, xL);

    // ---- step loop: 6 dispatches/step ----
    for (int step = 0; step < 4; ++step) {
        k_gates<<<192, 256, 0, stream>>>((char*)xH, (char*)xL, (char*)hAH, (char*)hAL,
                                         gwH, gwL, 0, gip, ghp);
        k_combine<<<128, 256, 0, stream>>>(gip, ghp, b_ih0, b_hh0, hA, hAH, hAL);
        k_gates<<<192, 256, 0, stream>>>((char*)hAH, (char*)hAL, (char*)hBH, (char*)hBL,
                                         gwH, gwL, 1, gip, ghp);
        k_combine<<<128, 256, 0, stream>>>(gip, ghp, b_ih1, b_hh1, hB, hBH, hBL);
        k_logits<<<500, 256, 0, stream>>>((char*)hBH, (char*)hBL, out_w,
                                          out, step, pval, pidx);
        k_reduce_embed<<<64, 256, 0, stream>>>(pval, pidx, embed, xH, xL);
    }
}

// Round 12
// 349.353 us; speedup vs baseline: 1.1225x; 1.0080x over previous
//
#include <hip/hip_runtime.h>
#include <math.h>

// ReDrafterHead: B=64, H=4096, D=512, G3=1536, V=32000, STEPS=4
// Round 16 = R13/R15 (352.2us, reproduced best) + ONE isolated change:
// the 3 independent prologue split dispatches merged into R12's
// correctness-proven one-chunk-per-thread k_split_all (2688x256), saving
// 2 launch boundaries. R12-vs-R14 comparison shows this merge was neutral
// on kernel time (R12's regression was the fused argmax, not the split).
// Everything else byte-identical to R13: 4-wave/NT=64/64KiB GEMMs
// (2 blocks/CU), no out_w pre-split, in-kernel fp32 B-split for logits,
// dedicated reduce_embed. 27 dispatches.

typedef __attribute__((ext_vector_type(8))) short short8;   // 8 bf16
typedef __attribute__((ext_vector_type(4))) float f32x4;

__device__ __forceinline__ unsigned short f2bf_rne(float x) {
    unsigned u = __float_as_uint(x);
    unsigned r = (u + 0x7fffu + ((u >> 16) & 1u)) >> 16;
    return (unsigned short)r;
}
// hi = truncate; lo = RNE of residual. 3-pass MFMA error ~2^-16 rel.
__device__ __forceinline__ void split2(float x, unsigned short& hi, unsigned short& lo) {
    unsigned u = __float_as_uint(x);
    hi = (unsigned short)(u >> 16);
    float r = x - __uint_as_float(u & 0xffff0000u);
    lo = f2bf_rne(r);
}

// store one element into swizzled bf16 hi/lo planes, row stride 512 elems.
__device__ __forceinline__ void store_plane(unsigned short* hiP, unsigned short* loP,
                                            int m, int d, float v) {
    int s = d >> 6, cl = (d >> 3) & 7, e = d & 7;
    int off = m * 512 + s * 64 + ((cl ^ (m & 7)) * 8) + e;
    unsigned short hi, lo; split2(v, hi, lo);
    hiP[off] = hi; loP[off] = lo;
}

__device__ __forceinline__ void gload16(const void* g, void* lds) {
    __builtin_amdgcn_global_load_lds(
        (const __attribute__((address_space(1))) unsigned int*)g,
        (__attribute__((address_space(3))) unsigned int*)lds, 16, 0, 0);
}

// ---------------------------------------------------------------------------
// Weight pre-split: W[N][K] fp32 -> swizzled bf16 planes, tile-major:
// ushort off = ((nt*(K/64) + ks)*128 + row)*64 + ((c8&7)^(row&7))*8
// ---------------------------------------------------------------------------
__device__ __forceinline__ void split_w_body(
    const float* __restrict__ W, unsigned short* __restrict__ H,
    unsigned short* __restrict__ L, size_t g, int kclog)
{
    int n  = (int)(g >> kclog);
    int c8 = (int)g & ((1 << kclog) - 1);
    const float* src = W + g * 8;
    float4 v0 = *(const float4*)src;
    float4 v1 = *(const float4*)(src + 4);
    unsigned short h[8], l[8];
    split2(v0.x,h[0],l[0]); split2(v0.y,h[1],l[1]); split2(v0.z,h[2],l[2]); split2(v0.w,h[3],l[3]);
    split2(v1.x,h[4],l[4]); split2(v1.y,h[5],l[5]); split2(v1.z,h[6],l[6]); split2(v1.w,h[7],l[7]);
    uint4 ph = make_uint4((unsigned)h[0]|((unsigned)h[1]<<16), (unsigned)h[2]|((unsigned)h[3]<<16),
                          (unsigned)h[4]|((unsigned)h[5]<<16), (unsigned)h[6]|((unsigned)h[7]<<16));
    uint4 pl = make_uint4((unsigned)l[0]|((unsigned)l[1]<<16), (unsigned)l[2]|((unsigned)l[3]<<16),
                          (unsigned)l[4]|((unsigned)l[5]<<16), (unsigned)l[6]|((unsigned)l[7]<<16));
    int nt = n >> 7, row = n & 127;
    int ksi = c8 >> 3;
    int slot = (c8 & 7) ^ (row & 7);
    int tpr = 1 << (kclog - 3);                 // tiles per row-tile = K/64
    size_t off = ((size_t)(nt * tpr + ksi) * 128 + row) * 64 + slot * 8;
    *(uint4*)(H + off) = ph;
    *(uint4*)(L + off) = pl;
}

// split hidden[64,4096] fp32 -> swizzled bf16 planes (row stride 8192 B)
__device__ __forceinline__ void split_a_body(
    const float* __restrict__ hidden, char* __restrict__ hidH,
    char* __restrict__ hidL, int g)
{
    int m = g >> 9;
    int cc = g & 511;
    int s = cc >> 3, cl = cc & 7;
    const float* src = hidden + m * 4096 + cc * 8;
    float4 v0 = *(const float4*)src;
    float4 v1 = *(const float4*)(src + 4);
    unsigned short h[8], l[8];
    split2(v0.x,h[0],l[0]); split2(v0.y,h[1],l[1]); split2(v0.z,h[2],l[2]); split2(v0.w,h[3],l[3]);
    split2(v1.x,h[4],l[4]); split2(v1.y,h[5],l[5]); split2(v1.z,h[6],l[6]); split2(v1.w,h[7],l[7]);
    uint4 ph = make_uint4((unsigned)h[0]|((unsigned)h[1]<<16), (unsigned)h[2]|((unsigned)h[3]<<16),
                          (unsigned)h[4]|((unsigned)h[5]<<16), (unsigned)h[6]|((unsigned)h[7]<<16));
    uint4 pl = make_uint4((unsigned)l[0]|((unsigned)l[1]<<16), (unsigned)l[2]|((unsigned)l[3]<<16),
                          (unsigned)l[4]|((unsigned)l[5]<<16), (unsigned)l[6]|((unsigned)l[7]<<16));
    int off = m * 8192 + s * 128 + ((cl ^ (m & 7)) * 16);
    *(uint4*)(hidH + off) = ph;
    *(uint4*)(hidL + off) = pl;
}

// ---------------------------------------------------------------------------
// P1: one dispatch, one chunk per thread: GRU mats + in_w + hidden.
// 688128 chunks = grid 2688 x 256 exactly. (R12-validated body.)
// ---------------------------------------------------------------------------
__global__ __launch_bounds__(256) void k_split_all(
    const float* __restrict__ w_ih0, const float* __restrict__ w_hh0,
    const float* __restrict__ w_ih1, const float* __restrict__ w_hh1,
    const float* __restrict__ in_w, const float* __restrict__ hidden,
    unsigned short* __restrict__ gwH, unsigned short* __restrict__ gwL,
    unsigned short* __restrict__ inH, unsigned short* __restrict__ inL,
    char* __restrict__ hidH, char* __restrict__ hidL)
{
    size_t u = (size_t)blockIdx.x * 256 + threadIdx.x;     // < 688128
    if (u < 393216) {
        int mat = (int)(u / 98304);
        const float* W = mat == 0 ? w_ih0 : mat == 1 ? w_hh0
                       : mat == 2 ? w_ih1 : w_hh1;
        split_w_body(W, gwH + (size_t)mat * 786432, gwL + (size_t)mat * 786432,
                     u % 98304, 6);
    } else if (u < 655360) {
        split_w_body(in_w, inH, inL, u - 393216, 9);
    } else {
        split_a_body(hidden, hidH, hidL, (int)(u - 655360));
    }
}

// ---------------------------------------------------------------------------
// Shared MFMA inner core: one 64-k tile from LDS buffers into acc[4].
// ---------------------------------------------------------------------------
__device__ __forceinline__ void mfma_core(
    const unsigned short* __restrict__ AsH0, const unsigned short* __restrict__ AsL0,
    const unsigned short* __restrict__ BsH0, const unsigned short* __restrict__ BsL0,
    int wv, int lr, int lh, f32x4* acc)
{
#pragma unroll
    for (int kk2 = 0; kk2 < 2; ++kk2) {
        int aoff = lr * 64 + (((kk2 * 4 + lh) ^ (lr & 7)) * 8);
        short8 ah[4], al[4];
#pragma unroll
        for (int mt = 0; mt < 4; ++mt) {
            ah[mt] = *(const short8*)(AsH0 + mt * 1024 + aoff);
            al[mt] = *(const short8*)(AsL0 + mt * 1024 + aoff);
        }
        int brow = wv * 16 + lr;
        int boff = brow * 64 + (((kk2 * 4 + lh) ^ (brow & 7)) * 8);
        short8 bh = *(const short8*)(BsH0 + boff);
        short8 bl = *(const short8*)(BsL0 + boff);
#pragma unroll
        for (int mt = 0; mt < 4; ++mt) {
            acc[mt] = __builtin_amdgcn_mfma_f32_16x16x32_bf16(ah[mt], bh, acc[mt], 0, 0, 0);
            acc[mt] = __builtin_amdgcn_mfma_f32_16x16x32_bf16(ah[mt], bl, acc[mt], 0, 0, 0);
            acc[mt] = __builtin_amdgcn_mfma_f32_16x16x32_bf16(al[mt], bh, acc[mt], 0, 0, 0);
        }
    }
}

__device__ __forceinline__ void epilogue_write(
    float* __restrict__ C, int ldc, int n0, int wv, int lr, int lh, const f32x4* acc)
{
#pragma unroll
    for (int mt = 0; mt < 4; ++mt)
#pragma unroll
        for (int i = 0; i < 4; ++i) {
            int mm = mt * 16 + lh * 4 + i;
            C[mm * ldc + n0 + wv * 16 + lr] = acc[mt][i];
        }
}

// ---------------------------------------------------------------------------
// 4-wave plane GEMM (256 threads), NT=64, 64 KiB LDS -> 2 blocks/CU.
// C[0..63][n0..n0+63] over nk k-steps. A: swizzled planes (stride AstrideB,
// start col akk0). B: tiled planes; btileU already includes the half-tile
// offset (rows [0,64) of the 64-col N-slice).
// ---------------------------------------------------------------------------
__device__ __forceinline__ void mfma_gemm4(
    const char* __restrict__ AH, const char* __restrict__ AL, int AstrideB, int akk0,
    const unsigned short* __restrict__ BH, const unsigned short* __restrict__ BL,
    size_t btileU, int nk,
    float* __restrict__ C, int ldc, int n0,
    unsigned short (*AsH)[4096], unsigned short (*AsL)[4096],
    unsigned short (*BsH)[4096], unsigned short (*BsL)[4096])
{
    const int tid  = threadIdx.x;
    const int wv   = tid >> 6;
    const int lane = tid & 63;
    const int lr   = lane & 15;
    const int lh   = lane >> 4;
    const int ar1  = wv * 16 + (lane >> 3);   // A staging row (call 1)
    const int acp  = lane & 7;                // A staging chunk

    f32x4 acc[4];
#pragma unroll
    for (int i = 0; i < 4; ++i) acc[i] = (f32x4){0.f, 0.f, 0.f, 0.f};

    auto stage = [&](int t, int p) {
        const int kaB = (akk0 + t * 64) * 2;
        gload16(AH + ar1 * AstrideB + kaB + acp * 16,       (char*)AsH[p] + wv * 2048);
        gload16(AH + (ar1 + 8) * AstrideB + kaB + acp * 16, (char*)AsH[p] + wv * 2048 + 1024);
        gload16(AL + ar1 * AstrideB + kaB + acp * 16,       (char*)AsL[p] + wv * 2048);
        gload16(AL + (ar1 + 8) * AstrideB + kaB + acp * 16, (char*)AsL[p] + wv * 2048 + 1024);
        const char* bH = (const char*)BH + (btileU + (size_t)t * 8192) * 2;
        const char* bL = (const char*)BL + (btileU + (size_t)t * 8192) * 2;
        gload16(bH + wv * 2048 +        lane * 16, (char*)BsH[p] + wv * 2048);
        gload16(bH + wv * 2048 + 1024 + lane * 16, (char*)BsH[p] + wv * 2048 + 1024);
        gload16(bL + wv * 2048 +        lane * 16, (char*)BsL[p] + wv * 2048);
        gload16(bL + wv * 2048 + 1024 + lane * 16, (char*)BsL[p] + wv * 2048 + 1024);
    };

    stage(0, 0);
    __syncthreads();

    for (int t = 0; t < nk; ++t) {
        const int p = t & 1;
        if (t + 1 < nk) stage(t + 1, p ^ 1);   // prefetch hides under MFMA
        mfma_core(AsH[p], AsL[p], BsH[p], BsL[p], wv, lr, lh, acc);
        __syncthreads();
    }

    epilogue_write(C, ldc, n0, wv, lr, lh, acc);
}

#define DECLARE_LDS4() \
    __shared__ alignas(16) unsigned short AsH[2][4096]; \
    __shared__ alignas(16) unsigned short AsL[2][4096]; \
    __shared__ alignas(16) unsigned short BsH[2][4096]; \
    __shared__ alignas(16) unsigned short BsL[2][4096];   /* 64 KiB */

// ---------------------------------------------------------------------------
// in_proj: part[ks][64][512] = hidden @ in_w^T.
// 128 blocks x 256 thr (8 nt2 x 16 ks), klen=256 (4 k-steps), NT=64.
// ---------------------------------------------------------------------------
__global__ __launch_bounds__(256) void k_inproj(
    const char* __restrict__ hidH, const char* __restrict__ hidL,
    const unsigned short* __restrict__ WH, const unsigned short* __restrict__ WL,
    float* __restrict__ part)
{
    DECLARE_LDS4();
    int nt2 = blockIdx.x & 7;                 // 0..7 (N-tile of 64)
    int ks  = blockIdx.x >> 3;                // 0..15
    size_t btile = (size_t)((nt2 >> 1) * 64 + ks * 4) * 8192 + (size_t)(nt2 & 1) * 4096;
    mfma_gemm4(hidH, hidL, 8192, ks * 256,
               WH, WL, btile, 4,
               part + ks * 32768, 512, nt2 * 64,
               AsH, AsL, BsH, BsL);
}

__global__ __launch_bounds__(256) void k_reduce_inproj(
    const float* __restrict__ part, const float* __restrict__ bias,
    float* __restrict__ hA, float* __restrict__ hB,
    unsigned short* hAH, unsigned short* hAL,
    unsigned short* hBH, unsigned short* hBL,
    unsigned short* xH,  unsigned short* xL)
{
    int i = blockIdx.x * 256 + threadIdx.x;   // < 32768
    int b = i >> 9;
    int d = i & 511;
    float s = bias[d];
#pragma unroll
    for (int ks = 0; ks < 16; ++ks) s += part[ks * 32768 + i];
    hA[i] = s;
    hB[i] = s;
    store_plane(hAH, hAL, b, d, s);
    store_plane(hBH, hBL, b, d, s);
    store_plane(xH,  xL,  b, d, 0.f);
}

// ---------------------------------------------------------------------------
// GRU gates, K-split 4, NT=64: 192 blocks x 256 thr (24 nt2 x 4 ks x 2 mat),
// klen=128 (2 k-steps). gw planes packed [w_ih0, w_hh0, w_ih1, w_hh1].
// ---------------------------------------------------------------------------
__global__ __launch_bounds__(256) void k_gates(
    const char* __restrict__ xH, const char* __restrict__ xL,
    const char* __restrict__ hH, const char* __restrict__ hL,
    const unsigned short* __restrict__ gwH, const unsigned short* __restrict__ gwL,
    int layer, float* __restrict__ gip, float* __restrict__ ghp)
{
    DECLARE_LDS4();
    int bx  = blockIdx.x;
    int nt2 = bx % 24;                        // 0..23 (N-tile of 64 over 1536)
    int ks  = (bx / 24) & 3;
    int mat = bx / 96;
    const char* AH = mat ? hH : xH;
    const char* AL = mat ? hL : xL;
    float* C = (mat ? ghp : gip) + ks * 98304;
    size_t btile = ((size_t)(layer * 2 + mat) * 96 + (nt2 >> 1) * 8 + ks * 2) * 8192
                 + (size_t)(nt2 & 1) * 4096;
    mfma_gemm4(AH, AL, 1024, ks * 128,
               gwH, gwL, btile, 2,
               C, 1536, nt2 * 64,
               AsH, AsL, BsH, BsL);
}

__global__ __launch_bounds__(256) void k_combine(
    const float* __restrict__ gip, const float* __restrict__ ghp,
    const float* __restrict__ b_ih, const float* __restrict__ b_hh,
    float* __restrict__ h, unsigned short* hH, unsigned short* hL)
{
    int i = blockIdx.x * 256 + threadIdx.x;   // < 32768
    int b = i >> 9;
    int d = i & 511;
    int base = b * 1536 + d;
    float ir = b_ih[d], iz = b_ih[d + 512], inn = b_ih[d + 1024];
    float hr = b_hh[d], hz = b_hh[d + 512], hn = b_hh[d + 1024];
#pragma unroll
    for (int ks = 0; ks < 4; ++ks) {
        const float* gi = gip + ks * 98304 + base;
        const float* gh = ghp + ks * 98304 + base;
        ir  += gi[0];    iz += gi[512];  inn += gi[1024];
        hr  += gh[0];    hz += gh[512];  hn  += gh[1024];
    }
    float r = 1.f / (1.f + expf(-(ir + hr)));
    float z = 1.f / (1.f + expf(-(iz + hz)));
    float n = tanhf(inn + r * hn);
    float hv = (1.f - z) * n + z * h[i];
    h[i] = hv;
    store_plane(hH, hL, b, d, hv);
}

// ---------------------------------------------------------------------------
// logits: 500 blocks x 256 threads (4 waves), NT=64, 64 KiB LDS ->
// 2 blocks/CU fully co-resident. B = out_w fp32 split in-register
// (issue-early/write-late); A = hB planes via 4-wave gload_lds identity.
// Per-block argmax partials pval/pidx.
// ---------------------------------------------------------------------------
__global__ __launch_bounds__(256) void k_logits(
    const char* __restrict__ hBH, const char* __restrict__ hBL,
    const float* __restrict__ out_w,
    float* __restrict__ out, int step,
    float* __restrict__ pval, int* __restrict__ pidx)
{
    __shared__ alignas(16) unsigned short AsH[2][4096];
    __shared__ alignas(16) unsigned short AsL[2][4096];
    __shared__ alignas(16) unsigned short BsH[2][4096];
    __shared__ alignas(16) unsigned short BsL[2][4096];    // 64 KiB

    const int tid  = threadIdx.x;
    const int wv   = tid >> 6;
    const int lane = tid & 63;
    const int lr   = lane & 15;
    const int lh   = lane >> 4;
    const int bx   = blockIdx.x;
    const int n0   = bx * 64;

    const int ar1 = wv * 16 + (lane >> 3);
    const int acp = lane & 7;
    auto stageA = [&](int kaB, int p) {
        gload16(hBH + ar1 * 1024 + kaB + acp * 16,       (char*)AsH[p] + wv * 2048);
        gload16(hBH + (ar1 + 8) * 1024 + kaB + acp * 16, (char*)AsH[p] + wv * 2048 + 1024);
        gload16(hBL + ar1 * 1024 + kaB + acp * 16,       (char*)AsL[p] + wv * 2048);
        gload16(hBL + (ar1 + 8) * 1024 + kaB + acp * 16, (char*)AsL[p] + wv * 2048 + 1024);
    };

    const int bn = tid >> 2, bq = tid & 3;
    const float* Wb = out_w + (size_t)(n0 + bn) * 512 + bq * 16;
    const int wo0 = bn * 64 + (((2 * bq)     ^ (bn & 7)) * 8);
    const int wo1 = bn * 64 + (((2 * bq + 1) ^ (bn & 7)) * 8);

    float4 r0, r1, r2, r3;
    auto loadB = [&](int t) {
        const float* s = Wb + t * 64;
        r0 = *(const float4*)s;       r1 = *(const float4*)(s + 4);
        r2 = *(const float4*)(s + 8); r3 = *(const float4*)(s + 12);
    };
    auto writeB = [&](int p) {
        unsigned short h[16], l[16];
        split2(r0.x,h[0],l[0]);   split2(r0.y,h[1],l[1]);   split2(r0.z,h[2],l[2]);   split2(r0.w,h[3],l[3]);
        split2(r1.x,h[4],l[4]);   split2(r1.y,h[5],l[5]);   split2(r1.z,h[6],l[6]);   split2(r1.w,h[7],l[7]);
        split2(r2.x,h[8],l[8]);   split2(r2.y,h[9],l[9]);   split2(r2.z,h[10],l[10]); split2(r2.w,h[11],l[11]);
        split2(r3.x,h[12],l[12]); split2(r3.y,h[13],l[13]); split2(r3.z,h[14],l[14]); split2(r3.w,h[15],l[15]);
        *(uint4*)(BsH[p] + wo0) = make_uint4(
            (unsigned)h[0]|((unsigned)h[1]<<16),  (unsigned)h[2]|((unsigned)h[3]<<16),
            (unsigned)h[4]|((unsigned)h[5]<<16),  (unsigned)h[6]|((unsigned)h[7]<<16));
        *(uint4*)(BsH[p] + wo1) = make_uint4(
            (unsigned)h[8]|((unsigned)h[9]<<16),  (unsigned)h[10]|((unsigned)h[11]<<16),
            (unsigned)h[12]|((unsigned)h[13]<<16),(unsigned)h[14]|((unsigned)h[15]<<16));
        *(uint4*)(BsL[p] + wo0) = make_uint4(
            (unsigned)l[0]|((unsigned)l[1]<<16),  (unsigned)l[2]|((unsigned)l[3]<<16),
            (unsigned)l[4]|((unsigned)l[5]<<16),  (unsigned)l[6]|((unsigned)l[7]<<16));
        *(uint4*)(BsL[p] + wo1) = make_uint4(
            (unsigned)l[8]|((unsigned)l[9]<<16),  (unsigned)l[10]|((unsigned)l[11]<<16),
            (unsigned)l[12]|((unsigned)l[13]<<16),(unsigned)l[14]|((unsigned)l[15]<<16));
    };

    f32x4 acc[4];
#pragma unroll
    for (int i = 0; i < 4; ++i) acc[i] = (f32x4){0.f, 0.f, 0.f, 0.f};

    loadB(0);
    stageA(0, 0);
    writeB(0);
    __syncthreads();
#pragma unroll
    for (int t = 0; t < 8; ++t) {
        const int p = t & 1;
        if (t < 7) { loadB(t + 1); stageA((t + 1) * 128, p ^ 1); }
        mfma_core(AsH[p], AsL[p], BsH[p], BsL[p], wv, lr, lh, acc);
        if (t < 7) writeB(p ^ 1);              // into the other buffer
        __syncthreads();
    }

    epilogue_write(out + step * 32000, 128000, n0, wv, lr, lh, acc);

    // ---- per-block argmax partials ----
    float* sv = (float*)&AsH[0][0];            // 256 floats
    int*   sc = (int*)&AsL[0][0];
#pragma unroll
    for (int mt = 0; mt < 4; ++mt)
#pragma unroll
        for (int i = 0; i < 4; ++i) {
            float v = acc[mt][i];
            int   c = n0 + wv * 16 + lr;
#pragma unroll
            for (int msk = 1; msk < 16; msk <<= 1) {
                float ov = __shfl_xor(v, msk, 64);
                int   oc = __shfl_xor(c, msk, 64);
                if (ov > v || (ov == v && oc < c)) { v = ov; c = oc; }
            }
            if (lr == 0) {
                int row = mt * 16 + lh * 4 + i;
                sv[wv * 64 + row] = v;
                sc[wv * 64 + row] = c;
            }
        }
    __syncthreads();
    if (tid < 64) {
        float v = sv[tid]; int c = sc[tid];
#pragma unroll
        for (int w = 1; w < 4; ++w) {
            float ov = sv[w * 64 + tid]; int oc = sc[w * 64 + tid];
            if (ov > v || (ov == v && oc < c)) { v = ov; c = oc; }
        }
        pval[bx * 64 + tid] = v;
        pidx[bx * 64 + tid] = c;
    }
}

// ---------------------------------------------------------------------------
// reduce 500 argmax partials (np first-occurrence) + embed gather -> x planes
// ---------------------------------------------------------------------------
__global__ __launch_bounds__(256) void k_reduce_embed(
    const float* __restrict__ pval, const int* __restrict__ pidx,
    const float* __restrict__ embed, unsigned short* xH, unsigned short* xL)
{
    __shared__ float sv[256];
    __shared__ int   sc[256];
    const int b = blockIdx.x;
    const int tid = threadIdx.x;
    float v = pval[tid * 64 + b];              // tid < 256 <= 500
    int   c = pidx[tid * 64 + b];
    if (tid + 256 < 500) {
        float ov = pval[(tid + 256) * 64 + b];
        int   oc = pidx[(tid + 256) * 64 + b];
        if (ov > v || (ov == v && oc < c)) { v = ov; c = oc; }
    }
    sv[tid] = v; sc[tid] = c;
    __syncthreads();
    for (int s = 128; s > 0; s >>= 1) {
        if (tid < s) {
            float ov = sv[tid + s]; int oc = sc[tid + s];
            if (ov > sv[tid] || (ov == sv[tid] && oc < sc[tid])) { sv[tid] = ov; sc[tid] = oc; }
        }
        __syncthreads();
    }
    int tok = sc[0];
    for (int j = tid; j < 512; j += 256)
        store_plane(xH, xL, b, j, embed[(size_t)tok * 512 + j]);
}

// ---------------------------------------------------------------------------
extern "C" void kernel_launch(void* const* d_in, const int* in_sizes, int n_in,
                              void* d_out, int out_size, void* d_ws, size_t ws_size,
                              hipStream_t stream)
{
    const float* hidden = (const float*)d_in[0];
    const float* in_w   = (const float*)d_in[1];
    const float* in_b   = (const float*)d_in[2];
    const float* w_ih0  = (const float*)d_in[3];
    const float* w_hh0  = (const float*)d_in[4];
    const float* b_ih0  = (const float*)d_in[5];
    const float* b_hh0  = (const float*)d_in[6];
    const float* w_ih1  = (const float*)d_in[7];
    const float* w_hh1  = (const float*)d_in[8];
    const float* b_ih1  = (const float*)d_in[9];
    const float* b_hh1  = (const float*)d_in[10];
    const float* embed  = (const float*)d_in[11];
    const float* out_w  = (const float*)d_in[12];
    float* out = (float*)d_out;                    // [64, 4, 32000]
    char*  ws  = (char*)d_ws;

    // ws layout (bytes) — ~28 MiB, all L3-resident
    float* hA  = (float*)(ws + 0);                 // 131072
    float* hB  = (float*)(ws + 131072);            // 131072
    unsigned short* xH  = (unsigned short*)(ws + 262144);   // 65536 each
    unsigned short* xL  = (unsigned short*)(ws + 327680);
    unsigned short* hAH = (unsigned short*)(ws + 393216);
    unsigned short* hAL = (unsigned short*)(ws + 458752);
    unsigned short* hBH = (unsigned short*)(ws + 524288);
    unsigned short* hBL = (unsigned short*)(ws + 589824);
    char* hidH = ws + 655360;                      // 524288
    char* hidL = ws + 1179648;                     // 524288
    float* gip = (float*)(ws + 1703936);           // 4*98304 fl = 1572864 B
    float* ghp = (float*)(ws + 3276800);           // 1572864 B
    float* pval = (float*)(ws + 4849664);          // 128000 (pad 131072)
    int*   pidx = (int*)  (ws + 4980736);          // 128000 (pad 131072)
    float* ipart = (float*)(ws + 5111808);         // 16*32768 fl = 2097152 B
    unsigned short* gwH = (unsigned short*)(ws + 7208960);   // 6291456
    unsigned short* gwL = (unsigned short*)(ws + 13500416);  // 6291456
    unsigned short* inH = (unsigned short*)(ws + 19791872);  // 4194304
    unsigned short* inL = (unsigned short*)(ws + 23986176);  // 4194304

    // ---- prologue: 3 dispatches (single merged split) ----
    k_split_all<<<2688, 256, 0, stream>>>(w_ih0, w_hh0, w_ih1, w_hh1,
                                          in_w, hidden,
                                          gwH, gwL, inH, inL, hidH, hidL);
    k_inproj<<<128, 256, 0, stream>>>(hidH, hidL, inH, inL, ipart);
    k_reduce_inproj<<<128, 256, 0, stream>>>(ipart, in_b, hA, hB,
                                             hAH, hAL, hBH, hBL, xH, xL);

    // ---- step loop: 6 dispatches/step ----
    for (int step = 0; step < 4; ++step) {
        k_gates<<<192, 256, 0, stream>>>((char*)xH, (char*)xL, (char*)hAH, (char*)hAL,
                                         gwH, gwL, 0, gip, ghp);
        k_combine<<<128, 256, 0, stream>>>(gip, ghp, b_ih0, b_hh0, hA, hAH, hAL);
        k_gates<<<192, 256, 0, stream>>>((char*)hAH, (char*)hAL, (char*)hBH, (char*)hBL,
                                         gwH, gwL, 1, gip, ghp);
        k_combine<<<128, 256, 0, stream>>>(gip, ghp, b_ih1, b_hh1, hB, hBH, hBL);
        k_logits<<<500, 256, 0, stream>>>((char*)hBH, (char*)hBL, out_w,
                                          out, step, pval, pidx);
        k_reduce_embed<<<64, 256, 0, stream>>>(pval, pidx, embed, xH, xL);
    }
}